// Round 1
// baseline (3198.531 us; speedup 1.0000x reference)
//
#include <hip/hip_runtime.h>

// ---------------------------------------------------------------------------
// StochasticKeyNet — key insight: decode_i(relu(encode_i(y))) == relu(y)
// because diag > 0.  So all intermediate perm/diag pairs cancel; only the
// first decode (perm0/diag0) and the final encode (perm11/diag11) remain.
// Activations are (C*H*W+1, B=128) with batch innermost == CHWN layout.
// ---------------------------------------------------------------------------

#define B 128

// v[perm[j]] = x[j] / diag[j]   (scatter form of decode)
__global__ void decode_kernel(const float* __restrict__ x, const int* __restrict__ perm,
                              const float* __restrict__ diag, float* __restrict__ v, int nrows) {
    int row = blockIdx.x * 8 + (threadIdx.x >> 5);
    if (row >= nrows) return;
    int lane = threadIdx.x & 31;
    int p = perm[row];
    float inv = 1.0f / diag[row];
    float4 val = ((const float4*)(x + (size_t)row * B))[lane];
    val.x *= inv; val.y *= inv; val.z *= inv; val.w *= inv;
    ((float4*)(v + (size_t)p * B))[lane] = val;
}

// out[j] = diag[j] * y[perm[j]]   (gather form of encode), no relu
__global__ void encode_kernel(const float* __restrict__ y, const int* __restrict__ perm,
                              const float* __restrict__ diag, float* __restrict__ out, int nrows) {
    int row = blockIdx.x * 8 + (threadIdx.x >> 5);
    if (row >= nrows) return;
    int lane = threadIdx.x & 31;
    int p = perm[row];
    float d = diag[row];
    float4 val = ((const float4*)(y + (size_t)p * B))[lane];
    val.x *= d; val.y *= d; val.z *= d; val.w *= d;
    ((float4*)(out + (size_t)row * B))[lane] = val;
}

// Conv in CHWN layout, fused bias*t and relu.  One block = 1 output pixel
// x 32 output channels.  256 threads = 32 n-groups (float4 over batch) x 8
// co-groups; each thread accumulates 4 co rows (strided by 8).
template <int KS>
__global__ __launch_bounds__(256) void conv_relu_kernel(
    const float* __restrict__ v, const float* __restrict__ w,
    const float* __restrict__ bias, float* __restrict__ y,
    int Ci, int Hi, int Wi, int Co, int Ho, int Wo, int stride, int pad)
{
    const int p = blockIdx.x;
    const int ho = p / Wo, wo = p % Wo;
    const int co_base = blockIdx.y * 32;
    const int lane = threadIdx.x & 31;
    const int cg = threadIdx.x >> 5;

    const float4 t4 = ((const float4*)(v + (size_t)Ci * Hi * Wi * B))[lane];

    float4 acc[4];
    const float* wp[4];
    bool valid[4];
#pragma unroll
    for (int r = 0; r < 4; ++r) {
        int co = co_base + r * 8 + cg;
        valid[r] = (co < Co);
        int coc = valid[r] ? co : (Co - 1);
        wp[r] = w + (size_t)coc * Ci * KS * KS;
        float bb = bias[coc];
        acc[r].x = bb * t4.x; acc[r].y = bb * t4.y;
        acc[r].z = bb * t4.z; acc[r].w = bb * t4.w;
    }

    const int hi0 = ho * stride - pad;
    const int wi0 = wo * stride - pad;

    for (int ci = 0; ci < Ci; ++ci) {
        const float* xbase = v + (size_t)ci * Hi * Wi * B;
        const int wci = ci * KS * KS;
#pragma unroll
        for (int kh = 0; kh < KS; ++kh) {
            int hi = hi0 + kh;
            if (hi < 0 || hi >= Hi) continue;
#pragma unroll
            for (int kw = 0; kw < KS; ++kw) {
                int wi = wi0 + kw;
                if (wi < 0 || wi >= Wi) continue;
                float4 x4 = ((const float4*)(xbase + ((size_t)hi * Wi + wi) * B))[lane];
#pragma unroll
                for (int r = 0; r < 4; ++r) {
                    float wt = wp[r][wci + kh * KS + kw];
                    acc[r].x = fmaf(wt, x4.x, acc[r].x);
                    acc[r].y = fmaf(wt, x4.y, acc[r].y);
                    acc[r].z = fmaf(wt, x4.z, acc[r].z);
                    acc[r].w = fmaf(wt, x4.w, acc[r].w);
                }
            }
        }
    }

    const size_t HW = (size_t)Ho * Wo;
#pragma unroll
    for (int r = 0; r < 4; ++r) {
        if (!valid[r]) continue;
        int co = co_base + r * 8 + cg;
        float4 o;
        o.x = fmaxf(acc[r].x, 0.f); o.y = fmaxf(acc[r].y, 0.f);
        o.z = fmaxf(acc[r].z, 0.f); o.w = fmaxf(acc[r].w, 0.f);
        ((float4*)(y + ((size_t)co * HW + p) * B))[lane] = o;
    }
    // t row passes through (with relu, like every other row)
    if (blockIdx.x == 0 && blockIdx.y == 0 && threadIdx.x < 32) {
        float4 o;
        o.x = fmaxf(t4.x, 0.f); o.y = fmaxf(t4.y, 0.f);
        o.z = fmaxf(t4.z, 0.f); o.w = fmaxf(t4.w, 0.f);
        ((float4*)(y + (size_t)Co * HW * B))[threadIdx.x] = o;
    }
}

// FC: y[r,n] = b[r]*t[n] + sum_k w[r,k]*v[k,n]; block R copies t row.
__global__ void fc_kernel(const float* __restrict__ v, const float* __restrict__ w,
                          const float* __restrict__ b, float* __restrict__ y,
                          int K, int R, int do_relu) {
    int r = blockIdx.x;
    int n = threadIdx.x;
    float t = v[(size_t)K * B + n];
    float val;
    if (r == R) {
        val = t;
    } else {
        float acc = b[r] * t;
        const float* wr = w + (size_t)r * K;
        for (int k = 0; k < K; ++k)
            acc = fmaf(wr[k], v[(size_t)k * B + n], acc);
        val = acc;
    }
    if (do_relu) val = fmaxf(val, 0.f);
    y[(size_t)r * B + n] = val;
}

struct ConvDesc { int Ci, Hi, Wi, Co, Ho, Wo, ks, st, pd; };
static const ConvDesc CD[9] = {
    {  3, 32, 32,  96, 32, 32, 3, 1, 1},
    { 96, 32, 32,  96, 32, 32, 3, 1, 1},
    { 96, 32, 32,  96, 16, 16, 3, 2, 1},
    { 96, 16, 16, 192, 16, 16, 3, 1, 1},
    {192, 16, 16, 192, 16, 16, 3, 1, 1},
    {192, 16, 16, 192,  8,  8, 3, 2, 1},
    {192,  8,  8, 192,  8,  8, 3, 1, 1},
    {192,  8,  8, 192,  8,  8, 1, 1, 0},
    {192,  8,  8,  10,  8,  8, 1, 1, 0},
};

extern "C" void kernel_launch(void* const* d_in, const int* in_sizes, int n_in,
                              void* d_out, int out_size, void* d_ws, size_t ws_size,
                              hipStream_t stream) {
    const float* x0 = (const float*)d_in[0];
    const int*   perm[12];
    const float* diag[12];
    for (int i = 0; i < 12; ++i) {
        perm[i] = (const int*)d_in[1 + 2 * i];
        diag[i] = (const float*)d_in[2 + 2 * i];
    }
    const float* w[9];
    const float* bi[9];
    for (int j = 0; j < 9; ++j) {
        w[j]  = (const float*)d_in[25 + 2 * j];
        bi[j] = (const float*)d_in[26 + 2 * j];
    }
    const float* fw1 = (const float*)d_in[43];
    const float* fb1 = (const float*)d_in[44];
    const float* fw2 = (const float*)d_in[45];
    const float* fb2 = (const float*)d_in[46];
    float* out = (float*)d_out;

    const size_t BUF_BYTES = (size_t)98305 * B * sizeof(float);
    float* bufA = (float*)d_ws;
    float* bufB = (float*)((char*)d_ws + BUF_BYTES);

    // initial decode: x0 (3073 rows) -> bufA
    decode_kernel<<<(3073 + 7) / 8, 256, 0, stream>>>(x0, perm[0], diag[0], bufA, 3073);

    float* cur = bufA;
    float* nxt = bufB;
    for (int i = 0; i < 9; ++i) {
        const ConvDesc& c = CD[i];
        dim3 grid(c.Ho * c.Wo, (c.Co + 31) / 32);
        if (c.ks == 3)
            conv_relu_kernel<3><<<grid, 256, 0, stream>>>(cur, w[i], bi[i], nxt,
                c.Ci, c.Hi, c.Wi, c.Co, c.Ho, c.Wo, c.st, c.pd);
        else
            conv_relu_kernel<1><<<grid, 256, 0, stream>>>(cur, w[i], bi[i], nxt,
                c.Ci, c.Hi, c.Wi, c.Co, c.Ho, c.Wo, c.st, c.pd);
        float* tmp = cur; cur = nxt; nxt = tmp;
    }

    // fc1: 640 -> 100, relu
    fc_kernel<<<101, B, 0, stream>>>(cur, fw1, fb1, nxt, 640, 100, 1);
    { float* tmp = cur; cur = nxt; nxt = tmp; }
    // fc2: 100 -> 10, no relu
    fc_kernel<<<11, B, 0, stream>>>(cur, fw2, fb2, nxt, 100, 10, 0);
    { float* tmp = cur; cur = nxt; nxt = tmp; }

    // final encode: 11 rows -> d_out
    encode_kernel<<<(11 + 7) / 8, 256, 0, stream>>>(cur, perm[11], diag[11], out, 11);
}

// Round 2
// 636.965 us; speedup vs baseline: 5.0215x; 5.0215x over previous
//
#include <hip/hip_runtime.h>

// ---------------------------------------------------------------------------
// StochasticKeyNet:  decode_i(relu(encode_i(y))) == relu(y)  (diag > 0), so
// only the first decode and last encode survive.  Convs run as implicit-GEMM
// f16 MFMA (16x16x32) with fp32 accumulation, activations packed as
// [ci/8][h][w][n][ci%8] f16 so every A/B fragment is one contiguous 16B/lane
// global load (no LDS).  FC tail stays fp32.
// ---------------------------------------------------------------------------

#define B 128
#define ZPAD 2048   // leading zero page (elements) in each packed act buffer

typedef _Float16 f16_t;
typedef __attribute__((ext_vector_type(8))) _Float16 f16x8;
typedef __attribute__((ext_vector_type(4))) _Float16 f16x4;
typedef __attribute__((ext_vector_type(4))) float f32x4;

// ---------------- fp32 helpers (unchanged from passing round) ----------------

__global__ void decode_kernel(const float* __restrict__ x, const int* __restrict__ perm,
                              const float* __restrict__ diag, float* __restrict__ v, int nrows) {
    int row = blockIdx.x * 8 + (threadIdx.x >> 5);
    if (row >= nrows) return;
    int lane = threadIdx.x & 31;
    int p = perm[row];
    float inv = 1.0f / diag[row];
    float4 val = ((const float4*)(x + (size_t)row * B))[lane];
    val.x *= inv; val.y *= inv; val.z *= inv; val.w *= inv;
    ((float4*)(v + (size_t)p * B))[lane] = val;
}

__global__ void encode_kernel(const float* __restrict__ y, const int* __restrict__ perm,
                              const float* __restrict__ diag, float* __restrict__ out, int nrows) {
    int row = blockIdx.x * 8 + (threadIdx.x >> 5);
    if (row >= nrows) return;
    int lane = threadIdx.x & 31;
    int p = perm[row];
    float d = diag[row];
    float4 val = ((const float4*)(y + (size_t)p * B))[lane];
    val.x *= d; val.y *= d; val.z *= d; val.w *= d;
    ((float4*)(out + (size_t)row * B))[lane] = val;
}

__global__ void fc_kernel(const float* __restrict__ v, const float* __restrict__ w,
                          const float* __restrict__ b, float* __restrict__ y,
                          int K, int R, int do_relu) {
    int r = blockIdx.x;
    int n = threadIdx.x;
    float t = v[(size_t)K * B + n];
    float val;
    if (r == R) {
        val = t;
    } else {
        float acc = b[r] * t;
        const float* wr = w + (size_t)r * K;
        for (int k = 0; k < K; ++k)
            acc = fmaf(wr[k], v[(size_t)k * B + n], acc);
        val = acc;
    }
    if (do_relu) val = fmaxf(val, 0.f);
    y[(size_t)r * B + n] = val;
}

// ---------------- prep: pack decoded input to f16 [cg][p][n][8] -------------

__global__ void pack_input_kernel(const float* __restrict__ v, f16_t* __restrict__ xout,
                                  float* __restrict__ tout) {
    int idx = blockIdx.x * 256 + threadIdx.x;   // 1024*128 threads
    int p = idx >> 7, n = idx & 127;
    f16x8 o = {};
    o[0] = (f16_t)v[(size_t)(0 * 1024 + p) * B + n];
    o[1] = (f16_t)v[(size_t)(1 * 1024 + p) * B + n];
    o[2] = (f16_t)v[(size_t)(2 * 1024 + p) * B + n];
    *(f16x8*)(xout + ZPAD + (size_t)p * 1024 + n * 8) = o;
    if (idx < B) tout[idx] = v[(size_t)3072 * B + idx];
}

// ---------------- prep: pack all conv weights/biases to f16 -----------------

struct WArgs {
    const float* w[9]; const float* b[9];
    int Ci[9], Co[9], KS[9], Cp[9], NCG[9];
    int woff[10]; int boff[10];
};

__global__ void pack_weights_kernel(WArgs A, f16_t* __restrict__ wp, float* __restrict__ bp,
                                    f16_t* __restrict__ x8a, f16_t* __restrict__ x8b) {
    int idx = blockIdx.x * 256 + threadIdx.x;
    if (idx < ZPAD) { x8a[idx] = (f16_t)0.f; x8b[idx] = (f16_t)0.f; }
    if (idx < A.boff[9]) {
        int l = 0;
        while (idx >= A.boff[l + 1]) ++l;
        int co = idx - A.boff[l];
        bp[idx] = (co < A.Co[l]) ? A.b[l][co] : 0.f;
    }
    if (idx >= A.woff[9]) return;
    int l = 0;
    while (idx >= A.woff[l + 1]) ++l;
    int e = idx - A.woff[l];
    int j = e & 7;
    int t1 = e >> 3;
    int Cp = A.Cp[l];
    int co = t1 % Cp;
    int gg = t1 / Cp;
    int ncg = A.NCG[l];
    int tap = gg / ncg, cg = gg - tap * ncg;
    int ks = A.KS[l];
    int kh = tap / ks, kw = tap - kh * ks;
    int ci = cg * 8 + j;
    float val = 0.f;
    if (co < A.Co[l] && tap < ks * ks && ci < A.Ci[l])
        val = A.w[l][(((size_t)co * A.Ci[l] + ci) * ks + kh) * ks + kw];
    wp[idx] = (f16_t)val;
}

// ---------------- the MFMA conv ---------------------------------------------
// wave = one output pixel (all 128 batch cols) x 64 output channels
// block = 4 waves = 4 pixels;  grid = (HWo/4, ceil(Co/64))

template <int KS, bool F32OUT>
__global__ __launch_bounds__(256, 1) void conv_mfma_kernel(
    const f16_t* __restrict__ xin, const float* __restrict__ t_in,
    const f16_t* __restrict__ wp, const float* __restrict__ bp,
    f16_t* __restrict__ xout, float* __restrict__ t_out, float* __restrict__ f32out,
    int Hi, int Wi, int Wo_log2, int HWo, int stride, int pad,
    int NCG, int nchunk, int KGr, int Co, int Co_pad)
{
    const int wave = threadIdx.x >> 6;
    const int lane = threadIdx.x & 63;
    const int q = lane >> 4;       // quad -> k-group within chunk, C rows q*4..q*4+3
    const int r = lane & 15;       // A: co row / B,C: column n (mod 16)
    const int p = blockIdx.x * 4 + wave;
    const int ho = p >> Wo_log2;
    const int wo = p & ((1 << Wo_log2) - 1);
    const int co0 = blockIdx.y * 64;
    const f16_t* xdata = xin + ZPAD;

    float tv[8];
#pragma unroll
    for (int ns = 0; ns < 8; ++ns) tv[ns] = t_in[ns * 16 + r];

    f32x4 acc[4][8];
#pragma unroll
    for (int ms = 0; ms < 4; ++ms) {
        float4 b4 = *(const float4*)(bp + co0 + ms * 16 + q * 4);
#pragma unroll
        for (int ns = 0; ns < 8; ++ns) {
            acc[ms][ns][0] = b4.x * tv[ns];
            acc[ms][ns][1] = b4.y * tv[ns];
            acc[ms][ns][2] = b4.z * tv[ns];
            acc[ms][ns][3] = b4.w * tv[ns];
        }
    }

    // this quad's k-group g = 4c + q; track (tap, cg) incrementally
    int g = q;
    int tap = 0, cg = g;
    while (cg >= NCG) { cg -= NCG; ++tap; }
    int aoff = (q * Co_pad + co0 + r) * 8;
    const int astep = 4 * Co_pad * 8;
    const int hb = ho * stride - pad, wb = wo * stride - pad;

    for (int c = 0; c < nchunk; ++c) {
        int kh, kw;
        if (KS == 3) { kh = tap / 3; kw = tap - kh * 3; } else { kh = 0; kw = 0; }
        int hi = hb + kh, wi = wb + kw;
        bool valid = (g < KGr) & ((unsigned)hi < (unsigned)Hi) & ((unsigned)wi < (unsigned)Wi);
        int boff = ((cg * Hi + hi) * Wi + wi) << 10;   // *128*8 elements
        boff = valid ? boff : -ZPAD;                   // zero page
        const f16_t* bb = xdata + boff + r * 8;

        f16x8 bf[8];
#pragma unroll
        for (int ns = 0; ns < 8; ++ns) bf[ns] = *(const f16x8*)(bb + ns * 128);
        f16x8 af[4];
#pragma unroll
        for (int ms = 0; ms < 4; ++ms) af[ms] = *(const f16x8*)(wp + aoff + ms * 128);

#pragma unroll
        for (int ms = 0; ms < 4; ++ms)
#pragma unroll
            for (int ns = 0; ns < 8; ++ns)
                acc[ms][ns] = __builtin_amdgcn_mfma_f32_16x16x32_f16(af[ms], bf[ns], acc[ms][ns], 0, 0, 0);

        g += 4; aoff += astep;
        cg += 4;
        while (cg >= NCG) { cg -= NCG; ++tap; }
    }

    if (!F32OUT) {
#pragma unroll
        for (int ms = 0; ms < 4; ++ms) {
            if (co0 + ms * 16 >= Co) continue;          // Co is a multiple of 16 here
            int cob = co0 + ms * 16 + q * 4;            // 4 consecutive co rows
            int off0 = ((cob >> 3) * HWo + p) * 1024 + (cob & 7) + r * 8;
#pragma unroll
            for (int ns = 0; ns < 8; ++ns) {
                f16x4 h;
                h[0] = (f16_t)fmaxf(acc[ms][ns][0], 0.f);
                h[1] = (f16_t)fmaxf(acc[ms][ns][1], 0.f);
                h[2] = (f16_t)fmaxf(acc[ms][ns][2], 0.f);
                h[3] = (f16_t)fmaxf(acc[ms][ns][3], 0.f);
                *(f16x4*)(xout + ZPAD + off0 + ns * 128) = h;
            }
        }
        if (blockIdx.x == 0 && blockIdx.y == 0 && threadIdx.x < B)
            t_out[threadIdx.x] = fmaxf(t_in[threadIdx.x], 0.f);
    } else {
#pragma unroll
        for (int ms = 0; ms < 4; ++ms)
#pragma unroll
            for (int ns = 0; ns < 8; ++ns)
#pragma unroll
                for (int e = 0; e < 4; ++e) {
                    int co = co0 + ms * 16 + q * 4 + e;
                    if (co < Co)
                        f32out[((size_t)co * HWo + p) * B + ns * 16 + r] =
                            fmaxf(acc[ms][ns][e], 0.f);
                }
        if (blockIdx.x == 0 && blockIdx.y == 0 && threadIdx.x < B)
            f32out[(size_t)Co * HWo * B + threadIdx.x] = fmaxf(t_in[threadIdx.x], 0.f);
    }
}

// ---------------------------------------------------------------------------

extern "C" void kernel_launch(void* const* d_in, const int* in_sizes, int n_in,
                              void* d_out, int out_size, void* d_ws, size_t ws_size,
                              hipStream_t stream) {
    const float* x0 = (const float*)d_in[0];
    const int*   perm[12];
    const float* diag[12];
    for (int i = 0; i < 12; ++i) {
        perm[i] = (const int*)d_in[1 + 2 * i];
        diag[i] = (const float*)d_in[2 + 2 * i];
    }
    const float* wts[9];
    const float* bia[9];
    for (int j = 0; j < 9; ++j) {
        wts[j] = (const float*)d_in[25 + 2 * j];
        bia[j] = (const float*)d_in[26 + 2 * j];
    }
    const float* fw1 = (const float*)d_in[43];
    const float* fb1 = (const float*)d_in[44];
    const float* fw2 = (const float*)d_in[45];
    const float* fb2 = (const float*)d_in[46];
    float* out = (float*)d_out;

    // ----- layer tables -----
    static const int CiA[9]  = {3, 96, 96, 96, 192, 192, 192, 192, 192};
    static const int CoA[9]  = {96, 96, 96, 192, 192, 192, 192, 192, 10};
    static const int KSA[9]  = {3, 3, 3, 3, 3, 3, 3, 1, 1};
    static const int CpA[9]  = {128, 128, 128, 192, 192, 192, 192, 192, 64};
    static const int NCGA[9] = {1, 12, 12, 12, 24, 24, 24, 24, 24};
    static const int KGRA[9] = {9, 108, 108, 108, 216, 216, 216, 24, 24};
    static const int NCHK[9] = {3, 27, 27, 27, 54, 54, 54, 6, 6};
    static const int HiA[9]  = {32, 32, 32, 16, 16, 16, 8, 8, 8};
    static const int WoL[9]  = {5, 5, 4, 4, 4, 3, 3, 3, 3};
    static const int HWoA[9] = {1024, 1024, 256, 256, 256, 64, 64, 64, 64};
    static const int STA[9]  = {1, 1, 2, 1, 1, 2, 1, 1, 1};
    static const int PDA[9]  = {1, 1, 1, 1, 1, 1, 1, 0, 0};

    // ----- workspace layout -----
    char* wsb = (char*)d_ws;
    const size_t BUF_F32  = 1574912;                               // >= 3073*128*4
    const size_t X8_BYTES = (size_t)(ZPAD + 12 * 1024 * 1024) * 2; // 25,169,920
    float* bufA = (float*)wsb;
    float* bufB = (float*)(wsb + BUF_F32);
    f16_t* x8a  = (f16_t*)(wsb + 2 * BUF_F32);
    f16_t* x8b  = (f16_t*)(wsb + 2 * BUF_F32 + X8_BYTES);
    f16_t* wpb  = (f16_t*)(wsb + 2 * BUF_F32 + 2 * X8_BYTES);
    const size_t WP_BYTES = 2888704;                               // >= 1,443,840*2, aligned
    float* bpb  = (float*)(wsb + 2 * BUF_F32 + 2 * X8_BYTES + WP_BYTES);
    float* t0   = (float*)((char*)bpb + 8192);
    float* t1   = t0 + 256;

    // ----- pack weights/bias + zero the zero-pages (every call) -----
    WArgs WA;
    int wo = 0, bo = 0;
    for (int l = 0; l < 9; ++l) {
        WA.w[l] = wts[l]; WA.b[l] = bia[l];
        WA.Ci[l] = CiA[l]; WA.Co[l] = CoA[l]; WA.KS[l] = KSA[l];
        WA.Cp[l] = CpA[l]; WA.NCG[l] = NCGA[l];
        WA.woff[l] = wo; wo += NCHK[l] * 4 * CpA[l] * 8;
        WA.boff[l] = bo; bo += CpA[l];
    }
    WA.woff[9] = wo; WA.boff[9] = bo;
    pack_weights_kernel<<<(wo + 255) / 256, 256, 0, stream>>>(WA, wpb, bpb, x8a, x8b);

    // ----- initial decode + pack -----
    decode_kernel<<<(3073 + 7) / 8, 256, 0, stream>>>(x0, perm[0], diag[0], bufA, 3073);
    pack_input_kernel<<<131072 / 256, 256, 0, stream>>>(bufA, x8a, t0);

    // ----- conv stack -----
    f16_t* xin = x8a; f16_t* xout = x8b;
    float* tin = t0;  float* tout = t1;
    for (int l = 0; l < 9; ++l) {
        dim3 grid(HWoA[l] / 4, (CoA[l] + 63) / 64);
        const f16_t* wpl = wpb + WA.woff[l];
        const float* bpl = bpb + WA.boff[l];
        if (KSA[l] == 3) {
            conv_mfma_kernel<3, false><<<grid, 256, 0, stream>>>(
                xin, tin, wpl, bpl, xout, tout, nullptr,
                HiA[l], HiA[l], WoL[l], HWoA[l], STA[l], PDA[l],
                NCGA[l], NCHK[l], KGRA[l], CoA[l], CpA[l]);
        } else if (l != 8) {
            conv_mfma_kernel<1, false><<<grid, 256, 0, stream>>>(
                xin, tin, wpl, bpl, xout, tout, nullptr,
                HiA[l], HiA[l], WoL[l], HWoA[l], STA[l], PDA[l],
                NCGA[l], NCHK[l], KGRA[l], CoA[l], CpA[l]);
        } else {
            conv_mfma_kernel<1, true><<<grid, 256, 0, stream>>>(
                xin, tin, wpl, bpl, nullptr, nullptr, bufA,
                HiA[l], HiA[l], WoL[l], HWoA[l], STA[l], PDA[l],
                NCGA[l], NCHK[l], KGRA[l], CoA[l], CpA[l]);
        }
        f16_t* xt = xin; xin = xout; xout = xt;
        float* tt = tin; tin = tout; tout = tt;
    }

    // ----- FC tail (fp32) + final encode -----
    fc_kernel<<<101, B, 0, stream>>>(bufA, fw1, fb1, bufB, 640, 100, 1);
    fc_kernel<<<11, B, 0, stream>>>(bufB, fw2, fb2, bufA, 100, 10, 0);
    encode_kernel<<<2, 256, 0, stream>>>(bufA, perm[11], diag[11], out, 11);
}

// Round 3
// 484.102 us; speedup vs baseline: 6.6071x; 1.3158x over previous
//
#include <hip/hip_runtime.h>

// ---------------------------------------------------------------------------
// StochasticKeyNet:  decode_i(relu(encode_i(y))) == relu(y)  (diag > 0), so
// only the first decode and last encode survive.  Convs run as implicit-GEMM
// f16 MFMA (16x16x32) with fp32 accumulation, activations packed as
// [ci/8][h][w][n][ci%8] f16 so every A/B fragment is one contiguous 16B/lane
// global load (no LDS).  FC tail fp32 with unroll-8 latency pipelining.
// ---------------------------------------------------------------------------

#define B 128
#define ZPAD 2048   // leading zero page (elements) in each packed act buffer

typedef _Float16 f16_t;
typedef __attribute__((ext_vector_type(8))) _Float16 f16x8;
typedef __attribute__((ext_vector_type(4))) _Float16 f16x4;
typedef __attribute__((ext_vector_type(4))) float f32x4;

// ---------------- fp32 helpers ----------------------------------------------

__global__ void decode_kernel(const float* __restrict__ x, const int* __restrict__ perm,
                              const float* __restrict__ diag, float* __restrict__ v, int nrows) {
    int row = blockIdx.x * 8 + (threadIdx.x >> 5);
    if (row >= nrows) return;
    int lane = threadIdx.x & 31;
    int p = perm[row];
    float inv = 1.0f / diag[row];
    float4 val = ((const float4*)(x + (size_t)row * B))[lane];
    val.x *= inv; val.y *= inv; val.z *= inv; val.w *= inv;
    ((float4*)(v + (size_t)p * B))[lane] = val;
}

__global__ void encode_kernel(const float* __restrict__ y, const int* __restrict__ perm,
                              const float* __restrict__ diag, float* __restrict__ out, int nrows) {
    int row = blockIdx.x * 8 + (threadIdx.x >> 5);
    if (row >= nrows) return;
    int lane = threadIdx.x & 31;
    int p = perm[row];
    float d = diag[row];
    float4 val = ((const float4*)(y + (size_t)p * B))[lane];
    val.x *= d; val.y *= d; val.z *= d; val.w *= d;
    ((float4*)(out + (size_t)row * B))[lane] = val;
}

// FC with unroll-8 / 8 independent accumulators so loads pipeline instead of
// paying full L2 latency per iteration (round-2 counters: VGPR=4, 150us —
// pure dependent-chain latency).
__global__ void fc_kernel(const float* __restrict__ v, const float* __restrict__ w,
                          const float* __restrict__ b, float* __restrict__ y,
                          int K, int R, int do_relu) {
    int r = blockIdx.x;
    int n = threadIdx.x;
    float t = v[(size_t)K * B + n];
    float val;
    if (r == R) {
        val = t;
    } else {
        float a0 = 0.f, a1 = 0.f, a2 = 0.f, a3 = 0.f;
        float a4 = 0.f, a5 = 0.f, a6 = 0.f, a7 = 0.f;
        const float* wr = w + (size_t)r * K;
        int k = 0;
        for (; k + 8 <= K; k += 8) {
            float4 w0 = *(const float4*)(wr + k);
            float4 w1 = *(const float4*)(wr + k + 4);
            float x0 = v[(size_t)(k + 0) * B + n];
            float x1 = v[(size_t)(k + 1) * B + n];
            float x2 = v[(size_t)(k + 2) * B + n];
            float x3 = v[(size_t)(k + 3) * B + n];
            float x4 = v[(size_t)(k + 4) * B + n];
            float x5 = v[(size_t)(k + 5) * B + n];
            float x6 = v[(size_t)(k + 6) * B + n];
            float x7 = v[(size_t)(k + 7) * B + n];
            a0 = fmaf(w0.x, x0, a0);
            a1 = fmaf(w0.y, x1, a1);
            a2 = fmaf(w0.z, x2, a2);
            a3 = fmaf(w0.w, x3, a3);
            a4 = fmaf(w1.x, x4, a4);
            a5 = fmaf(w1.y, x5, a5);
            a6 = fmaf(w1.z, x6, a6);
            a7 = fmaf(w1.w, x7, a7);
        }
        for (; k < K; ++k)
            a0 = fmaf(wr[k], v[(size_t)k * B + n], a0);
        val = b[r] * t + ((a0 + a1) + (a2 + a3)) + ((a4 + a5) + (a6 + a7));
    }
    if (do_relu) val = fmaxf(val, 0.f);
    y[(size_t)r * B + n] = val;
}

// ---------------- prep: pack decoded input to f16 [cg][p][n][8] -------------

__global__ void pack_input_kernel(const float* __restrict__ v, f16_t* __restrict__ xout,
                                  float* __restrict__ tout) {
    int idx = blockIdx.x * 256 + threadIdx.x;   // 1024*128 threads
    int p = idx >> 7, n = idx & 127;
    f16x8 o = {};
    o[0] = (f16_t)v[(size_t)(0 * 1024 + p) * B + n];
    o[1] = (f16_t)v[(size_t)(1 * 1024 + p) * B + n];
    o[2] = (f16_t)v[(size_t)(2 * 1024 + p) * B + n];
    *(f16x8*)(xout + ZPAD + (size_t)p * 1024 + n * 8) = o;
    if (idx < B) tout[idx] = v[(size_t)3072 * B + idx];
}

// ---------------- prep: pack all conv weights/biases to f16 -----------------

struct WArgs {
    const float* w[9]; const float* b[9];
    int Ci[9], Co[9], KS[9], Cp[9], NCG[9];
    int woff[10]; int boff[10];
};

__global__ void pack_weights_kernel(WArgs A, f16_t* __restrict__ wp, float* __restrict__ bp,
                                    f16_t* __restrict__ x8a, f16_t* __restrict__ x8b) {
    int idx = blockIdx.x * 256 + threadIdx.x;
    if (idx < ZPAD) { x8a[idx] = (f16_t)0.f; x8b[idx] = (f16_t)0.f; }
    if (idx < A.boff[9]) {
        int l = 0;
        while (idx >= A.boff[l + 1]) ++l;
        int co = idx - A.boff[l];
        bp[idx] = (co < A.Co[l]) ? A.b[l][co] : 0.f;
    }
    if (idx >= A.woff[9]) return;
    int l = 0;
    while (idx >= A.woff[l + 1]) ++l;
    int e = idx - A.woff[l];
    int j = e & 7;
    int t1 = e >> 3;
    int Cp = A.Cp[l];
    int co = t1 % Cp;
    int gg = t1 / Cp;
    int ncg = A.NCG[l];
    int tap = gg / ncg, cg = gg - tap * ncg;
    int ks = A.KS[l];
    int kh = tap / ks, kw = tap - kh * ks;
    int ci = cg * 8 + j;
    float val = 0.f;
    if (co < A.Co[l] && tap < ks * ks && ci < A.Ci[l])
        val = A.w[l][(((size_t)co * A.Ci[l] + ci) * ks + kh) * ks + kw];
    wp[idx] = (f16_t)val;
}

// ---------------- the MFMA conv ---------------------------------------------
// wave = one output pixel (all 128 batch cols) x 64 output channels
// block = 4 waves = 4 pixels;  grid = (HWo/4, ceil(Co/64))

template <int KS, bool F32OUT>
__global__ __launch_bounds__(256, 1) void conv_mfma_kernel(
    const f16_t* __restrict__ xin, const float* __restrict__ t_in,
    const f16_t* __restrict__ wp, const float* __restrict__ bp,
    f16_t* __restrict__ xout, float* __restrict__ t_out, float* __restrict__ f32out,
    int Hi, int Wi, int Wo_log2, int HWo, int stride, int pad,
    int NCG, int nchunk, int KGr, int Co, int Co_pad)
{
    const int wave = threadIdx.x >> 6;
    const int lane = threadIdx.x & 63;
    const int q = lane >> 4;       // quad -> k-group within chunk, C rows q*4..q*4+3
    const int r = lane & 15;       // A: co row / B,C: column n (mod 16)
    const int p = blockIdx.x * 4 + wave;
    const int ho = p >> Wo_log2;
    const int wo = p & ((1 << Wo_log2) - 1);
    const int co0 = blockIdx.y * 64;
    const f16_t* xdata = xin + ZPAD;

    float tv[8];
#pragma unroll
    for (int ns = 0; ns < 8; ++ns) tv[ns] = t_in[ns * 16 + r];

    f32x4 acc[4][8];
#pragma unroll
    for (int ms = 0; ms < 4; ++ms) {
        float4 b4 = *(const float4*)(bp + co0 + ms * 16 + q * 4);
#pragma unroll
        for (int ns = 0; ns < 8; ++ns) {
            acc[ms][ns][0] = b4.x * tv[ns];
            acc[ms][ns][1] = b4.y * tv[ns];
            acc[ms][ns][2] = b4.z * tv[ns];
            acc[ms][ns][3] = b4.w * tv[ns];
        }
    }

    // this quad's k-group g = 4c + q; track (tap, cg) incrementally
    int g = q;
    int tap = 0, cg = g;
    while (cg >= NCG) { cg -= NCG; ++tap; }
    int aoff = (q * Co_pad + co0 + r) * 8;
    const int astep = 4 * Co_pad * 8;
    const int hb = ho * stride - pad, wb = wo * stride - pad;

    for (int c = 0; c < nchunk; ++c) {
        int kh, kw;
        if (KS == 3) { kh = tap / 3; kw = tap - kh * 3; } else { kh = 0; kw = 0; }
        int hi = hb + kh, wi = wb + kw;
        bool valid = (g < KGr) & ((unsigned)hi < (unsigned)Hi) & ((unsigned)wi < (unsigned)Wi);
        int boff = ((cg * Hi + hi) * Wi + wi) << 10;   // *128*8 elements
        boff = valid ? boff : -ZPAD;                   // zero page
        const f16_t* bb = xdata + boff + r * 8;

        f16x8 bf[8];
#pragma unroll
        for (int ns = 0; ns < 8; ++ns) bf[ns] = *(const f16x8*)(bb + ns * 128);
        f16x8 af[4];
#pragma unroll
        for (int ms = 0; ms < 4; ++ms) af[ms] = *(const f16x8*)(wp + aoff + ms * 128);

#pragma unroll
        for (int ms = 0; ms < 4; ++ms)
#pragma unroll
            for (int ns = 0; ns < 8; ++ns)
                acc[ms][ns] = __builtin_amdgcn_mfma_f32_16x16x32_f16(af[ms], bf[ns], acc[ms][ns], 0, 0, 0);

        g += 4; aoff += astep;
        cg += 4;
        while (cg >= NCG) { cg -= NCG; ++tap; }
    }

    if (!F32OUT) {
#pragma unroll
        for (int ms = 0; ms < 4; ++ms) {
            if (co0 + ms * 16 >= Co) continue;          // Co is a multiple of 16 here
            int cob = co0 + ms * 16 + q * 4;            // 4 consecutive co rows
            int off0 = ((cob >> 3) * HWo + p) * 1024 + (cob & 7) + r * 8;
#pragma unroll
            for (int ns = 0; ns < 8; ++ns) {
                f16x4 h;
                h[0] = (f16_t)fmaxf(acc[ms][ns][0], 0.f);
                h[1] = (f16_t)fmaxf(acc[ms][ns][1], 0.f);
                h[2] = (f16_t)fmaxf(acc[ms][ns][2], 0.f);
                h[3] = (f16_t)fmaxf(acc[ms][ns][3], 0.f);
                *(f16x4*)(xout + ZPAD + off0 + ns * 128) = h;
            }
        }
        if (blockIdx.x == 0 && blockIdx.y == 0 && threadIdx.x < B)
            t_out[threadIdx.x] = fmaxf(t_in[threadIdx.x], 0.f);
    } else {
#pragma unroll
        for (int ms = 0; ms < 4; ++ms)
#pragma unroll
            for (int ns = 0; ns < 8; ++ns)
#pragma unroll
                for (int e = 0; e < 4; ++e) {
                    int co = co0 + ms * 16 + q * 4 + e;
                    if (co < Co)
                        f32out[((size_t)co * HWo + p) * B + ns * 16 + r] =
                            fmaxf(acc[ms][ns][e], 0.f);
                }
        if (blockIdx.x == 0 && blockIdx.y == 0 && threadIdx.x < B)
            f32out[(size_t)Co * HWo * B + threadIdx.x] = fmaxf(t_in[threadIdx.x], 0.f);
    }
}

// ---------------------------------------------------------------------------

extern "C" void kernel_launch(void* const* d_in, const int* in_sizes, int n_in,
                              void* d_out, int out_size, void* d_ws, size_t ws_size,
                              hipStream_t stream) {
    const float* x0 = (const float*)d_in[0];
    const int*   perm[12];
    const float* diag[12];
    for (int i = 0; i < 12; ++i) {
        perm[i] = (const int*)d_in[1 + 2 * i];
        diag[i] = (const float*)d_in[2 + 2 * i];
    }
    const float* wts[9];
    const float* bia[9];
    for (int j = 0; j < 9; ++j) {
        wts[j] = (const float*)d_in[25 + 2 * j];
        bia[j] = (const float*)d_in[26 + 2 * j];
    }
    const float* fw1 = (const float*)d_in[43];
    const float* fb1 = (const float*)d_in[44];
    const float* fw2 = (const float*)d_in[45];
    const float* fb2 = (const float*)d_in[46];
    float* out = (float*)d_out;

    // ----- layer tables -----
    static const int CiA[9]  = {3, 96, 96, 96, 192, 192, 192, 192, 192};
    static const int CoA[9]  = {96, 96, 96, 192, 192, 192, 192, 192, 10};
    static const int KSA[9]  = {3, 3, 3, 3, 3, 3, 3, 1, 1};
    static const int CpA[9]  = {128, 128, 128, 192, 192, 192, 192, 192, 64};
    static const int NCGA[9] = {1, 12, 12, 12, 24, 24, 24, 24, 24};
    static const int KGRA[9] = {9, 108, 108, 108, 216, 216, 216, 24, 24};
    static const int NCHK[9] = {3, 27, 27, 27, 54, 54, 54, 6, 6};
    static const int HiA[9]  = {32, 32, 32, 16, 16, 16, 8, 8, 8};
    static const int WoL[9]  = {5, 5, 4, 4, 4, 3, 3, 3, 3};
    static const int HWoA[9] = {1024, 1024, 256, 256, 256, 64, 64, 64, 64};
    static const int STA[9]  = {1, 1, 2, 1, 1, 2, 1, 1, 1};
    static const int PDA[9]  = {1, 1, 1, 1, 1, 1, 1, 0, 0};

    // ----- workspace layout -----
    char* wsb = (char*)d_ws;
    const size_t BUF_F32  = 1574912;                               // >= 3073*128*4
    const size_t X8_BYTES = (size_t)(ZPAD + 12 * 1024 * 1024) * 2; // 25,169,920
    float* bufA = (float*)wsb;
    float* bufB = (float*)(wsb + BUF_F32);
    f16_t* x8a  = (f16_t*)(wsb + 2 * BUF_F32);
    f16_t* x8b  = (f16_t*)(wsb + 2 * BUF_F32 + X8_BYTES);
    f16_t* wpb  = (f16_t*)(wsb + 2 * BUF_F32 + 2 * X8_BYTES);
    const size_t WP_BYTES = 2888704;                               // >= 1,443,840*2, aligned
    float* bpb  = (float*)(wsb + 2 * BUF_F32 + 2 * X8_BYTES + WP_BYTES);
    float* t0   = (float*)((char*)bpb + 8192);
    float* t1   = t0 + 256;

    // ----- pack weights/bias + zero the zero-pages (every call) -----
    WArgs WA;
    int wo = 0, bo = 0;
    for (int l = 0; l < 9; ++l) {
        WA.w[l] = wts[l]; WA.b[l] = bia[l];
        WA.Ci[l] = CiA[l]; WA.Co[l] = CoA[l]; WA.KS[l] = KSA[l];
        WA.Cp[l] = CpA[l]; WA.NCG[l] = NCGA[l];
        WA.woff[l] = wo; wo += NCHK[l] * 4 * CpA[l] * 8;
        WA.boff[l] = bo; bo += CpA[l];
    }
    WA.woff[9] = wo; WA.boff[9] = bo;
    pack_weights_kernel<<<(wo + 255) / 256, 256, 0, stream>>>(WA, wpb, bpb, x8a, x8b);

    // ----- initial decode + pack -----
    decode_kernel<<<(3073 + 7) / 8, 256, 0, stream>>>(x0, perm[0], diag[0], bufA, 3073);
    pack_input_kernel<<<131072 / 256, 256, 0, stream>>>(bufA, x8a, t0);

    // ----- conv stack -----
    f16_t* xin = x8a; f16_t* xout = x8b;
    float* tin = t0;  float* tout = t1;
    for (int l = 0; l < 9; ++l) {
        dim3 grid(HWoA[l] / 4, (CoA[l] + 63) / 64);
        const f16_t* wpl = wpb + WA.woff[l];
        const float* bpl = bpb + WA.boff[l];
        if (KSA[l] == 3) {
            conv_mfma_kernel<3, false><<<grid, 256, 0, stream>>>(
                xin, tin, wpl, bpl, xout, tout, nullptr,
                HiA[l], HiA[l], WoL[l], HWoA[l], STA[l], PDA[l],
                NCGA[l], NCHK[l], KGRA[l], CoA[l], CpA[l]);
        } else if (l != 8) {
            conv_mfma_kernel<1, false><<<grid, 256, 0, stream>>>(
                xin, tin, wpl, bpl, xout, tout, nullptr,
                HiA[l], HiA[l], WoL[l], HWoA[l], STA[l], PDA[l],
                NCGA[l], NCHK[l], KGRA[l], CoA[l], CpA[l]);
        } else {
            conv_mfma_kernel<1, true><<<grid, 256, 0, stream>>>(
                xin, tin, wpl, bpl, nullptr, nullptr, bufA,
                HiA[l], HiA[l], WoL[l], HWoA[l], STA[l], PDA[l],
                NCGA[l], NCHK[l], KGRA[l], CoA[l], CpA[l]);
        }
        f16_t* xt = xin; xin = xout; xout = xt;
        float* tt = tin; tin = tout; tout = tt;
    }

    // ----- FC tail (fp32) + final encode -----
    fc_kernel<<<101, B, 0, stream>>>(bufA, fw1, fb1, bufB, 640, 100, 1);
    fc_kernel<<<11, B, 0, stream>>>(bufB, fw2, fb2, bufA, 100, 10, 0);
    encode_kernel<<<2, 256, 0, stream>>>(bufA, perm[11], diag[11], out, 11);
}

// Round 4
// 363.889 us; speedup vs baseline: 8.7898x; 1.3304x over previous
//
#include <hip/hip_runtime.h>

// ---------------------------------------------------------------------------
// StochasticKeyNet:  decode_i(relu(encode_i(y))) == relu(y)  (diag > 0), so
// only the first decode and last encode survive.  Convs run as implicit-GEMM
// f16 MFMA (16x16x32) with fp32 accumulation, activations packed as
// [ci/8][h][w][n][ci%8] f16 so every A/B fragment is one contiguous 16B/lane
// global load (no LDS).  R3: register double-buffered K-loop prefetch,
// XCD-contiguous block swizzle, 16-co/wave variant for small layers.
// ---------------------------------------------------------------------------

#define B 128
#define ZPAD 2048   // leading zero page (elements) in each packed act buffer

typedef _Float16 f16_t;
typedef __attribute__((ext_vector_type(8))) _Float16 f16x8;
typedef __attribute__((ext_vector_type(4))) _Float16 f16x4;
typedef __attribute__((ext_vector_type(4))) float f32x4;

// ---------------- fp32 helpers ----------------------------------------------

__global__ void decode_kernel(const float* __restrict__ x, const int* __restrict__ perm,
                              const float* __restrict__ diag, float* __restrict__ v, int nrows) {
    int row = blockIdx.x * 8 + (threadIdx.x >> 5);
    if (row >= nrows) return;
    int lane = threadIdx.x & 31;
    int p = perm[row];
    float inv = 1.0f / diag[row];
    float4 val = ((const float4*)(x + (size_t)row * B))[lane];
    val.x *= inv; val.y *= inv; val.z *= inv; val.w *= inv;
    ((float4*)(v + (size_t)p * B))[lane] = val;
}

__global__ void encode_kernel(const float* __restrict__ y, const int* __restrict__ perm,
                              const float* __restrict__ diag, float* __restrict__ out, int nrows) {
    int row = blockIdx.x * 8 + (threadIdx.x >> 5);
    if (row >= nrows) return;
    int lane = threadIdx.x & 31;
    int p = perm[row];
    float d = diag[row];
    float4 val = ((const float4*)(y + (size_t)p * B))[lane];
    val.x *= d; val.y *= d; val.z *= d; val.w *= d;
    ((float4*)(out + (size_t)row * B))[lane] = val;
}

// FC with unroll-8 / 8 independent accumulators (R2: VGPR=4 dependent-chain
// latency was 150us; this pipelines the loads).
__global__ void fc_kernel(const float* __restrict__ v, const float* __restrict__ w,
                          const float* __restrict__ b, float* __restrict__ y,
                          int K, int R, int do_relu) {
    int r = blockIdx.x;
    int n = threadIdx.x;
    float t = v[(size_t)K * B + n];
    float val;
    if (r == R) {
        val = t;
    } else {
        float a0 = 0.f, a1 = 0.f, a2 = 0.f, a3 = 0.f;
        float a4 = 0.f, a5 = 0.f, a6 = 0.f, a7 = 0.f;
        const float* wr = w + (size_t)r * K;
        int k = 0;
        for (; k + 8 <= K; k += 8) {
            float4 w0 = *(const float4*)(wr + k);
            float4 w1 = *(const float4*)(wr + k + 4);
            float x0 = v[(size_t)(k + 0) * B + n];
            float x1 = v[(size_t)(k + 1) * B + n];
            float x2 = v[(size_t)(k + 2) * B + n];
            float x3 = v[(size_t)(k + 3) * B + n];
            float x4 = v[(size_t)(k + 4) * B + n];
            float x5 = v[(size_t)(k + 5) * B + n];
            float x6 = v[(size_t)(k + 6) * B + n];
            float x7 = v[(size_t)(k + 7) * B + n];
            a0 = fmaf(w0.x, x0, a0);
            a1 = fmaf(w0.y, x1, a1);
            a2 = fmaf(w0.z, x2, a2);
            a3 = fmaf(w0.w, x3, a3);
            a4 = fmaf(w1.x, x4, a4);
            a5 = fmaf(w1.y, x5, a5);
            a6 = fmaf(w1.z, x6, a6);
            a7 = fmaf(w1.w, x7, a7);
        }
        for (; k < K; ++k)
            a0 = fmaf(wr[k], v[(size_t)k * B + n], a0);
        val = b[r] * t + ((a0 + a1) + (a2 + a3)) + ((a4 + a5) + (a6 + a7));
    }
    if (do_relu) val = fmaxf(val, 0.f);
    y[(size_t)r * B + n] = val;
}

// ---------------- prep: pack decoded input to f16 [cg][p][n][8] -------------

__global__ void pack_input_kernel(const float* __restrict__ v, f16_t* __restrict__ xout,
                                  float* __restrict__ tout) {
    int idx = blockIdx.x * 256 + threadIdx.x;   // 1024*128 threads
    int p = idx >> 7, n = idx & 127;
    f16x8 o = {};
    o[0] = (f16_t)v[(size_t)(0 * 1024 + p) * B + n];
    o[1] = (f16_t)v[(size_t)(1 * 1024 + p) * B + n];
    o[2] = (f16_t)v[(size_t)(2 * 1024 + p) * B + n];
    *(f16x8*)(xout + ZPAD + (size_t)p * 1024 + n * 8) = o;
    if (idx < B) tout[idx] = v[(size_t)3072 * B + idx];
}

// ---------------- prep: pack all conv weights/biases to f16 -----------------

struct WArgs {
    const float* w[9]; const float* b[9];
    int Ci[9], Co[9], KS[9], Cp[9], NCG[9];
    int woff[10]; int boff[10];
};

__global__ void pack_weights_kernel(WArgs A, f16_t* __restrict__ wp, float* __restrict__ bp,
                                    f16_t* __restrict__ x8a, f16_t* __restrict__ x8b) {
    int idx = blockIdx.x * 256 + threadIdx.x;
    if (idx < ZPAD) { x8a[idx] = (f16_t)0.f; x8b[idx] = (f16_t)0.f; }
    if (idx < A.boff[9]) {
        int l = 0;
        while (idx >= A.boff[l + 1]) ++l;
        int co = idx - A.boff[l];
        bp[idx] = (co < A.Co[l]) ? A.b[l][co] : 0.f;
    }
    if (idx >= A.woff[9]) return;
    int l = 0;
    while (idx >= A.woff[l + 1]) ++l;
    int e = idx - A.woff[l];
    int j = e & 7;
    int t1 = e >> 3;
    int Cp = A.Cp[l];
    int co = t1 % Cp;
    int gg = t1 / Cp;
    int ncg = A.NCG[l];
    int tap = gg / ncg, cg = gg - tap * ncg;
    int ks = A.KS[l];
    int kh = tap / ks, kw = tap - kh * ks;
    int ci = cg * 8 + j;
    float val = 0.f;
    if (co < A.Co[l] && tap < ks * ks && ci < A.Ci[l])
        val = A.w[l][(((size_t)co * A.Ci[l] + ci) * ks + kh) * ks + kw];
    wp[idx] = (f16_t)val;
}

// ---------------- the MFMA conv ---------------------------------------------
// MS=4: wave = 1 pixel x 64 co, block = 4 pixels          (large layers)
// MS=1: wave = 1 pixel x 16 co, block = 1 pixel x 64 co   (small layers)
// 1-D grid, XCD-contiguous swizzle: xcd = bid&7 owns pixel-blocks
// [xcd*PB8, (xcd+1)*PB8) for ALL co groups -> input slice fits its L2.
// K-loop register double-buffer: load chunk c+1 while MFMA'ing chunk c.

template <int KS, int MS, bool F32OUT>
__global__ __launch_bounds__(256, (MS == 1) ? 3 : 2) void conv_mfma_kernel(
    const f16_t* __restrict__ xin, const float* __restrict__ t_in,
    const f16_t* __restrict__ wp, const float* __restrict__ bp,
    f16_t* __restrict__ xout, float* __restrict__ t_out, float* __restrict__ f32out,
    int Hi, int Wi, int Wo_log2, int HWo, int stride, int pad,
    int NCG, int nchunk, int KGr, int Co, int Co_pad, int PB8, int CB)
{
    const int wave = threadIdx.x >> 6;
    const int lane = threadIdx.x & 63;
    const int q = lane >> 4;       // quad -> k-group within chunk, C rows q*4..q*4+3
    const int r = lane & 15;       // A: co row / B,C: column n (mod 16)

    const int gb  = blockIdx.x;
    const int xcd = gb & 7;
    const int j   = gb >> 3;
    const int cog = j % CB;
    const int pb  = xcd * PB8 + j / CB;

    const int p   = (MS == 4) ? (pb * 4 + wave) : pb;
    const int co0 = cog * 64 + ((MS == 1) ? wave * 16 : 0);

    const int ho = p >> Wo_log2;
    const int wo = p & ((1 << Wo_log2) - 1);
    const f16_t* xdata = xin + ZPAD;

    float tv[8];
#pragma unroll
    for (int ns = 0; ns < 8; ++ns) tv[ns] = t_in[ns * 16 + r];

    f32x4 acc[MS][8];
#pragma unroll
    for (int ms = 0; ms < MS; ++ms) {
        float4 b4 = *(const float4*)(bp + co0 + ms * 16 + q * 4);
#pragma unroll
        for (int ns = 0; ns < 8; ++ns) {
            acc[ms][ns][0] = b4.x * tv[ns];
            acc[ms][ns][1] = b4.y * tv[ns];
            acc[ms][ns][2] = b4.z * tv[ns];
            acc[ms][ns][3] = b4.w * tv[ns];
        }
    }

    const int hb = ho * stride - pad, wb = wo * stride - pad;

    // per-quad K-chunk state: g = 4c + q;  (tap, cg) tracked incrementally
    int g = q, tap = 0, cg = q;
    while (cg >= NCG) { cg -= NCG; ++tap; }

    f16x8 bf0[8], bf1[8], af0[MS], af1[MS];

    auto loadB = [&](f16x8* bf) {
        int kh = 0, kw = 0;
        if (KS == 3) { kh = tap / 3; kw = tap - kh * 3; }
        int hi = hb + kh, wi = wb + kw;
        bool v = (g < KGr) & ((unsigned)hi < (unsigned)Hi) & ((unsigned)wi < (unsigned)Wi);
        int boff = ((cg * Hi + hi) * Wi + wi) << 10;   // *128*8 elements
        const f16_t* bb = xdata + (v ? boff : -ZPAD) + r * 8;
#pragma unroll
        for (int ns = 0; ns < 8; ++ns) bf[ns] = *(const f16x8*)(bb + ns * 128);
    };
    auto loadA = [&](f16x8* af, int c) {
        int ac = c < nchunk ? c : nchunk - 1;          // clamp phantom chunks
        const f16_t* ap = wp + (((ac * 4 + q) * Co_pad) + co0 + r) * 8;
#pragma unroll
        for (int ms = 0; ms < MS; ++ms) af[ms] = *(const f16x8*)(ap + ms * 128);
    };
    auto advance = [&]() {
        g += 4; cg += 4;
        while (cg >= NCG) { cg -= NCG; ++tap; }
    };
    auto domfma = [&](f16x8* af, f16x8* bf) {
#pragma unroll
        for (int ms = 0; ms < MS; ++ms)
#pragma unroll
            for (int ns = 0; ns < 8; ++ns)
                acc[ms][ns] = __builtin_amdgcn_mfma_f32_16x16x32_f16(af[ms], bf[ns], acc[ms][ns], 0, 0, 0);
    };

    // phantom chunks (c >= nchunk) have g >= KGr -> B reads zero page -> no-op
    loadB(bf0); loadA(af0, 0); advance();
    const int nck2 = (nchunk + 1) & ~1;
    for (int c = 0; c < nck2; c += 2) {
        loadB(bf1); loadA(af1, c + 1); advance();
        domfma(af0, bf0);
        loadB(bf0); loadA(af0, c + 2); advance();
        domfma(af1, bf1);
    }

    if (!F32OUT) {
#pragma unroll
        for (int ms = 0; ms < MS; ++ms) {
            int cob = co0 + ms * 16 + q * 4;            // 4 consecutive co rows
            if (cob < Co) {
                int off0 = ((cob >> 3) * HWo + p) * 1024 + (cob & 7) + r * 8;
#pragma unroll
                for (int ns = 0; ns < 8; ++ns) {
                    f16x4 h;
                    h[0] = (f16_t)fmaxf(acc[ms][ns][0], 0.f);
                    h[1] = (f16_t)fmaxf(acc[ms][ns][1], 0.f);
                    h[2] = (f16_t)fmaxf(acc[ms][ns][2], 0.f);
                    h[3] = (f16_t)fmaxf(acc[ms][ns][3], 0.f);
                    *(f16x4*)(xout + ZPAD + off0 + ns * 128) = h;
                }
            }
        }
        if (gb == 0 && threadIdx.x < B)
            t_out[threadIdx.x] = fmaxf(t_in[threadIdx.x], 0.f);
    } else {
#pragma unroll
        for (int ms = 0; ms < MS; ++ms)
#pragma unroll
            for (int ns = 0; ns < 8; ++ns)
#pragma unroll
                for (int e = 0; e < 4; ++e) {
                    int co = co0 + ms * 16 + q * 4 + e;
                    if (co < Co)
                        f32out[((size_t)co * HWo + p) * B + ns * 16 + r] =
                            fmaxf(acc[ms][ns][e], 0.f);
                }
        if (gb == 0 && threadIdx.x < B)
            f32out[(size_t)Co * HWo * B + threadIdx.x] = fmaxf(t_in[threadIdx.x], 0.f);
    }
}

// ---------------------------------------------------------------------------

extern "C" void kernel_launch(void* const* d_in, const int* in_sizes, int n_in,
                              void* d_out, int out_size, void* d_ws, size_t ws_size,
                              hipStream_t stream) {
    const float* x0 = (const float*)d_in[0];
    const int*   perm[12];
    const float* diag[12];
    for (int i = 0; i < 12; ++i) {
        perm[i] = (const int*)d_in[1 + 2 * i];
        diag[i] = (const float*)d_in[2 + 2 * i];
    }
    const float* wts[9];
    const float* bia[9];
    for (int j = 0; j < 9; ++j) {
        wts[j] = (const float*)d_in[25 + 2 * j];
        bia[j] = (const float*)d_in[26 + 2 * j];
    }
    const float* fw1 = (const float*)d_in[43];
    const float* fb1 = (const float*)d_in[44];
    const float* fw2 = (const float*)d_in[45];
    const float* fb2 = (const float*)d_in[46];
    float* out = (float*)d_out;

    // ----- layer tables -----
    static const int CiA[9]  = {3, 96, 96, 96, 192, 192, 192, 192, 192};
    static const int CoA[9]  = {96, 96, 96, 192, 192, 192, 192, 192, 10};
    static const int KSA[9]  = {3, 3, 3, 3, 3, 3, 3, 1, 1};
    static const int CpA[9]  = {128, 128, 128, 192, 192, 192, 192, 192, 64};
    static const int NCGA[9] = {1, 12, 12, 12, 24, 24, 24, 24, 24};
    static const int KGRA[9] = {9, 108, 108, 108, 216, 216, 216, 24, 24};
    static const int NCHK[9] = {3, 27, 27, 27, 54, 54, 54, 6, 6};
    static const int HiA[9]  = {32, 32, 32, 16, 16, 16, 8, 8, 8};
    static const int WoL[9]  = {5, 5, 4, 4, 4, 3, 3, 3, 3};
    static const int HWoA[9] = {1024, 1024, 256, 256, 256, 64, 64, 64, 64};
    static const int STA[9]  = {1, 1, 2, 1, 1, 2, 1, 1, 1};
    static const int PDA[9]  = {1, 1, 1, 1, 1, 1, 1, 0, 0};
    static const int MSA[9]  = {4, 4, 1, 1, 1, 1, 1, 1, 1};

    // ----- workspace layout -----
    char* wsb = (char*)d_ws;
    const size_t BUF_F32  = 1574912;                               // >= 3073*128*4
    const size_t X8_BYTES = (size_t)(ZPAD + 12 * 1024 * 1024) * 2; // 25,169,920
    float* bufA = (float*)wsb;
    float* bufB = (float*)(wsb + BUF_F32);
    f16_t* x8a  = (f16_t*)(wsb + 2 * BUF_F32);
    f16_t* x8b  = (f16_t*)(wsb + 2 * BUF_F32 + X8_BYTES);
    f16_t* wpb  = (f16_t*)(wsb + 2 * BUF_F32 + 2 * X8_BYTES);
    const size_t WP_BYTES = 2888704;                               // >= 1,443,840*2, aligned
    float* bpb  = (float*)(wsb + 2 * BUF_F32 + 2 * X8_BYTES + WP_BYTES);
    float* t0   = (float*)((char*)bpb + 8192);
    float* t1   = t0 + 256;

    // ----- pack weights/bias + zero the zero-pages (every call) -----
    WArgs WA;
    int wo = 0, bo = 0;
    for (int l = 0; l < 9; ++l) {
        WA.w[l] = wts[l]; WA.b[l] = bia[l];
        WA.Ci[l] = CiA[l]; WA.Co[l] = CoA[l]; WA.KS[l] = KSA[l];
        WA.Cp[l] = CpA[l]; WA.NCG[l] = NCGA[l];
        WA.woff[l] = wo; wo += NCHK[l] * 4 * CpA[l] * 8;
        WA.boff[l] = bo; bo += CpA[l];
    }
    WA.woff[9] = wo; WA.boff[9] = bo;
    pack_weights_kernel<<<(wo + 255) / 256, 256, 0, stream>>>(WA, wpb, bpb, x8a, x8b);

    // ----- initial decode + pack -----
    decode_kernel<<<(3073 + 7) / 8, 256, 0, stream>>>(x0, perm[0], diag[0], bufA, 3073);
    pack_input_kernel<<<131072 / 256, 256, 0, stream>>>(bufA, x8a, t0);

    // ----- conv stack -----
    f16_t* xin = x8a; f16_t* xout = x8b;
    float* tin = t0;  float* tout = t1;
    for (int l = 0; l < 9; ++l) {
        const int ms = MSA[l];
        const int PB = HWoA[l] / (ms == 4 ? 4 : 1);
        const int CB = CpA[l] / 64;
        dim3 grid(PB * CB);
        const int PB8 = PB / 8;
        const f16_t* wpl = wpb + WA.woff[l];
        const float* bpl = bpb + WA.boff[l];
        if (l <= 1) {
            conv_mfma_kernel<3, 4, false><<<grid, 256, 0, stream>>>(
                xin, tin, wpl, bpl, xout, tout, nullptr,
                HiA[l], HiA[l], WoL[l], HWoA[l], STA[l], PDA[l],
                NCGA[l], NCHK[l], KGRA[l], CoA[l], CpA[l], PB8, CB);
        } else if (l <= 6) {
            conv_mfma_kernel<3, 1, false><<<grid, 256, 0, stream>>>(
                xin, tin, wpl, bpl, xout, tout, nullptr,
                HiA[l], HiA[l], WoL[l], HWoA[l], STA[l], PDA[l],
                NCGA[l], NCHK[l], KGRA[l], CoA[l], CpA[l], PB8, CB);
        } else if (l == 7) {
            conv_mfma_kernel<1, 1, false><<<grid, 256, 0, stream>>>(
                xin, tin, wpl, bpl, xout, tout, nullptr,
                HiA[l], HiA[l], WoL[l], HWoA[l], STA[l], PDA[l],
                NCGA[l], NCHK[l], KGRA[l], CoA[l], CpA[l], PB8, CB);
        } else {
            conv_mfma_kernel<1, 1, true><<<grid, 256, 0, stream>>>(
                xin, tin, wpl, bpl, nullptr, nullptr, bufA,
                HiA[l], HiA[l], WoL[l], HWoA[l], STA[l], PDA[l],
                NCGA[l], NCHK[l], KGRA[l], CoA[l], CpA[l], PB8, CB);
        }
        f16_t* xt = xin; xin = xout; xout = xt;
        float* tt = tin; tin = tout; tout = tt;
    }

    // ----- FC tail (fp32) + final encode -----
    fc_kernel<<<101, B, 0, stream>>>(bufA, fw1, fb1, bufB, 640, 100, 1);
    fc_kernel<<<11, B, 0, stream>>>(bufB, fw2, fb2, bufA, 100, 10, 0);
    encode_kernel<<<2, 256, 0, stream>>>(bufA, perm[11], diag[11], out, 11);
}